// Round 12
// baseline (197.831 us; speedup 1.0000x reference)
//
#include <hip/hip_runtime.h>
#include <hip/hip_bf16.h>

#define NB    2
#define NK    2048
#define NPTS  16384
#define NBK   4096            // NB*NK
#define MSAMP 65536.0f        // NBK*16 samples per scale for BN0/BN1
#define MROW  4096.0f         // rows for final BN

// spatial binning grid: cell = 0.8 (== r1), origin (-70.4, -40.0)
#define NCELLX 176
#define NCELLY 101
#define NCELLS 17776          // 176*101
#define CAP    24             // bucket capacity (mean 0.94 pts/cell; tail ~0)
#define CANDMAX 64            // staged candidates per keypoint (avg ~8.3)

#define NGRID  1024           // r12: 4 blocks/CU co-resident (was 512 x 2/CU)
#define KPB    4              // keypoints per block
#define NREP   32             // stats replicas (RMW chain depth 32)
#define NCTR   64             // split barrier counters (chain depth 16)

// device-scope (agent) relaxed atomic load — reads the coherence point.
#define AL(p) __hip_atomic_load((p), __ATOMIC_RELAXED, __HIP_MEMORY_SCOPE_AGENT)

// RETURNING atomic with sunk result: ack arrives only after the op is
// PERFORMED at the coherence point, so a following s_waitcnt vmcnt(0) gives
// "my writes are globally visible" (r4 post-mortem; r5..r11 proved it).
#define ATOMIC_ADD_ACK(p, v) do { \
  float _r = atomicAdd((p), (v)); \
  asm volatile("" :: "v"(_r)); } while (0)

// accumulate 14 BN0 moments (order matches bn0-param consumption)
#define ACC14(M, w, X, Y, Z, F) do { \
  M[0] += (w)*(X); M[1] += (w)*(Y); M[2] += (w)*(Z); M[3] += (w)*(F); \
  M[4] += (w)*(X)*(X); M[5] += (w)*(X)*(Y); M[6] += (w)*(X)*(Z); M[7] += (w)*(X)*(F); \
  M[8] += (w)*(Y)*(Y); M[9] += (w)*(Y)*(Z); M[10] += (w)*(Y)*(F); \
  M[11] += (w)*(Z)*(Z); M[12] += (w)*(Z)*(F); M[13] += (w)*(F)*(F); } while (0)

__device__ __forceinline__ int cell_of(float x, float y) {
  int cx = (int)floorf((x + 70.4f) * 1.25f);
  int cy = (int)floorf((y + 40.0f) * 1.25f);
  cx = min(max(cx, 0), NCELLX - 1);
  cy = min(max(cy, 0), NCELLY - 1);
  return cy * NCELLX + cx;
}

// Two-stage release-flag grid barrier (r7..r11-verified). Layout per
// instance: base[0..63] = counters, base[64..127] = release flags.
__device__ __forceinline__ void grid_barrier(int* base, int per, int myc) {
  asm volatile("s_waitcnt vmcnt(0)" ::: "memory");
  __syncthreads();
  const int t = threadIdx.x;
  int* ctr = base;
  int* rel = base + NCTR;
  if (t == 0) {
    int old = __hip_atomic_fetch_add(&ctr[myc], 1, __ATOMIC_RELAXED,
                                     __HIP_MEMORY_SCOPE_AGENT);
    asm volatile("" :: "v"(old));
  }
  if (blockIdx.x == 0) {
    if (t < NCTR) {
      while (AL(&ctr[t]) < per) __builtin_amdgcn_s_sleep(8);
    }
    __syncthreads();           // all counters observed by the whole block
    if (t < NCTR)
      __hip_atomic_store(&rel[t], 1, __ATOMIC_RELAXED,
                         __HIP_MEMORY_SCOPE_AGENT);
  } else {
    if (t == 0) {
      while (AL(&rel[myc]) == 0) __builtin_amdgcn_s_sleep(8);
    }
  }
  __syncthreads();
}

// ---------------------------------------------------------------------------
// K1: direct bucket-build (blocks 0..127) + BEV CHW->HWC transpose
// (blocks 128..2327), FLOAT4 both sides (r11-verified).
// cellcnt zeroed by the preceding memset.
// ---------------------------------------------------------------------------
__global__ __launch_bounds__(256) void bintrans_kernel(
    const float* __restrict__ pts, const float* __restrict__ pfeat,
    const float* __restrict__ bev,
    int* __restrict__ cellcnt, float4* __restrict__ bucketP,
    int* __restrict__ bucketI, float* __restrict__ bevT)
{
  __shared__ __align__(16) float ttile[64][65];
  const int t = threadIdx.x;

  if (blockIdx.x < 128) {
    const int i  = blockIdx.x * 256 + t;      // 0..32767
    const int b  = i >> 14;
    const int il = i & (NPTS - 1);
    const float* px = pts + (size_t)b * NPTS * 3;
    const float x = px[il*3+0], y = px[il*3+1], z = px[il*3+2];
    const float f = pfeat[(size_t)b * NPTS + il];
    const int c = b * NCELLS + cell_of(x, y);
    const int pos = atomicAdd(&cellcnt[c], 1);
    if (pos < CAP) {
      bucketP[(size_t)c * CAP + pos] = make_float4(x, y, z, f);
      bucketI[(size_t)c * CAP + pos] = il;
    }
    return;
  }

  // ---- TRANSPOSE role, float4 both sides (r11-verified)
  const int tb  = blockIdx.x - 128;     // 0..2199
  const int b   = tb / 1100;
  const int rem = tb % 1100;
  const int cg  = (rem / 275) * 64;     // channel group base
  const int sp0 = (rem % 275) * 64;     // spatial base (17600 = 275*64)
  const int lo = t & 15, hi = t >> 4;
  #pragma unroll
  for (int pass = 0; pass < 4; pass++) {
    const int ch = hi + pass * 16;      // 0..63
    const float4 v = *(const float4*)&bev[
        ((size_t)(b * 256 + cg + ch)) * 17600 + sp0 + lo * 4];
    ttile[ch][lo*4+0] = v.x;
    ttile[ch][lo*4+1] = v.y;
    ttile[ch][lo*4+2] = v.z;
    ttile[ch][lo*4+3] = v.w;
  }
  __syncthreads();
  #pragma unroll
  for (int pass = 0; pass < 4; pass++) {
    const int s = hi + pass * 16;       // 0..63
    float4 v;
    v.x = ttile[lo*4+0][s];
    v.y = ttile[lo*4+1][s];
    v.z = ttile[lo*4+2][s];
    v.w = ttile[lo*4+3][s];
    *(float4*)&bevT[((size_t)b * 17600 + sp0 + s) * 256 + cg + lo * 4] = v;
  }
}

// ---------------------------------------------------------------------------
// K2: mega-fused. grid 1024 x 256, 4 keypoints/block, 4 blocks/CU (r12:
// occupancy 2->4 waves/SIMD; r11's 21% occupancy was the binding constraint
// on the latency-bound gather/candidate/replica phases).
//   [gather BEV from bevT] [G-stage: 32 lanes prefetch candidates -> LDS]
//   [G-process: 4 lanes slot-assign, S0 adds]
//   bar0 [BN0: distributed replica read] [S: BN1 stats, h2 kept in regs]
//   bar1 [BN1: distributed replica read] [P: pool from carried h2; GEMM; S2]
//   bar2 [final BN: distributed replica read; relu; out from acc regs]
// Sync protocol r5..r11-verified; stats replicated x32.
// Grouping correctness vs reference: for cnt<=16 the slot SET is exact
// (order-free; BN stats sum over slots, pool is max); padding replicates the
// min-original-index hit == ref's idx[:, :1]; empty -> zeros.
// ---------------------------------------------------------------------------
__global__ __launch_bounds__(256, 4) void fused_kernel(
    const float* __restrict__ kp, const int* __restrict__ stridep,
    const float* __restrict__ bevT,
    const int* __restrict__ cellcnt, const float4* __restrict__ bucketP,
    const int* __restrict__ bucketI,
    const float* __restrict__ W0s0, const float* __restrict__ gm0s0, const float* __restrict__ bt0s0,
    const float* __restrict__ W0s1, const float* __restrict__ gm0s1, const float* __restrict__ bt0s1,
    const float* __restrict__ W1s0, const float* __restrict__ gm1s0, const float* __restrict__ bt1s0,
    const float* __restrict__ W1s1, const float* __restrict__ gm1s1, const float* __restrict__ bt1s1,
    const float* __restrict__ Wf, const float* __restrict__ gf, const float* __restrict__ bfp,
    float* __restrict__ S0r, float* __restrict__ S1r,
    float* __restrict__ S2sr, float* __restrict__ S2qr,
    int* __restrict__ ctrs, float* __restrict__ out)
{
  __shared__ float sW0a[64], sW0b[64], sW1a[256], sW1b[512], sP[160];
  __shared__ float skp[12];
  __shared__ float red[4][96];
  __shared__ float t2s[2][128], t2q[2][128];
  __shared__ float sA[128], sB[128];
  __shared__ float s0p[8][28], sS0[28];
  __shared__ __align__(16) float sF[KPB * 304];
  __shared__ float4 sG0[KPB][16], sG1[KPB][16];
  __shared__ __align__(16) float4 sCand[KPB][CANDMAX];
  __shared__ int sCandI[KPB][CANDMAX];
  __shared__ int sTot[KPB];
  __shared__ int scnt[2][KPB];
  const int t = threadIdx.x;
  const int bk0 = blockIdx.x * KPB;
  const int rep = blockIdx.x & (NREP - 1);
  const int myc = blockIdx.x & (NCTR - 1);

  if (t < 12) skp[t] = kp[(size_t)bk0 * 3 + t];
  if (t < 64) { sW0a[t] = W0s0[t]; sW0b[t] = W0s1[t]; }
  sW1a[t]       = W1s0[t];
  sW1b[t]       = W1s1[t];
  sW1b[t + 256] = W1s1[t + 256];
  for (int i = t; i < 4 * 96; i += 256) ((float*)red)[i] = 0.f;
  __syncthreads();

  // ---- BEV gather from bevT (HWC): channel t, 4 rows, 16 coalesced loads --
  {
    const float st = (float)(*stridep);
    const int b = bk0 >> 11;             // all 4 rows in same batch (4 | 2048)
    const size_t pb = (size_t)b * 17600 * 256;
    #pragma unroll
    for (int r = 0; r < KPB; r++) {
      const float x = (skp[r*3+0] - (-70.4f)) / 0.1f / st;
      const float y = (skp[r*3+1] - (-40.0f)) / 0.1f / st;
      const int xf = (int)floorf(x), yf = (int)floorf(y);
      const int x0 = min(max(xf, 0), 175), x1 = min(max(xf + 1, 0), 175);
      const int y0 = min(max(yf, 0), 99),  y1 = min(max(yf + 1, 0), 99);
      const float x0f = (float)x0, x1f = (float)x1, y0f = (float)y0, y1f = (float)y1;
      const float wa = (x1f - x) * (y1f - y);
      const float wb = (x1f - x) * (y - y0f);
      const float wc = (x - x0f) * (y1f - y);
      const float wd = (x - x0f) * (y - y0f);
      const float Ia = bevT[pb + (size_t)(y0 * 176 + x0) * 256 + t];
      const float Ib = bevT[pb + (size_t)(y1 * 176 + x0) * 256 + t];
      const float Ic = bevT[pb + (size_t)(y0 * 176 + x1) * 256 + t];
      const float Id = bevT[pb + (size_t)(y1 * 176 + x1) * 256 + t];
      sF[r * 304 + t] = Ia * wa + Ib * wb + Ic * wc + Id * wd;
    }
  }

  // ---- PHASE G-stage: 8 lanes per keypoint prefetch candidates to LDS ----
  if (t < 8 * KPB) {
    const int kpi = t >> 3, sub = t & 7;
    const int b   = (bk0 + kpi) >> 11;
    const float kx = skp[kpi*3+0], ky = skp[kpi*3+1];
    int cx = (int)floorf((kx + 70.4f) * 1.25f);
    int cy = (int)floorf((ky + 40.0f) * 1.25f);
    cx = min(max(cx, 1), NCELLX - 2);
    cy = min(max(cy, 1), NCELLY - 2);
    const int cb0 = b * NCELLS + (cy - 1) * NCELLX + cx - 1;
    // 3x3 window, row-major c9=0..8; lane sub owns c9=sub, lane 0 also c9=8
    const int cellS = cb0 + (sub / 3) * NCELLX + (sub % 3);
    const int cell8 = cb0 + 2 * NCELLX + 2;
    const int nS = min(cellcnt[cellS], CAP);
    const int n8 = (sub == 0) ? min(cellcnt[cell8], CAP) : 0;
    // exclusive prefix of nS within the 8-lane group
    int pre = nS;
    #pragma unroll
    for (int d = 1; d < 8; d <<= 1) {
      const int v = __shfl_up(pre, d, 8);
      if (sub >= d) pre += v;
    }
    const int offS  = pre - nS;
    const int tot07 = __shfl(pre, 7, 8);
    const float4* bp = bucketP + (size_t)cellS * CAP;
    const int*    bi = bucketI + (size_t)cellS * CAP;
    for (int j = 0; j < nS; ++j) {
      const int o = offS + j;
      if (o < CANDMAX) { sCand[kpi][o] = bp[j]; sCandI[kpi][o] = bi[j]; }
    }
    if (sub == 0) {
      const float4* bp8 = bucketP + (size_t)cell8 * CAP;
      const int*    bi8 = bucketI + (size_t)cell8 * CAP;
      for (int j = 0; j < n8; ++j) {
        const int o = tot07 + j;
        if (o < CANDMAX) { sCand[kpi][o] = bp8[j]; sCandI[kpi][o] = bi8[j]; }
      }
      sTot[kpi] = min(tot07 + n8, CANDMAX);
    }
  }
  __syncthreads();

  // ---- PHASE G-process: 1 lane/kp, order-dependent slot pass from LDS ----
  if (t < 8 * KPB && (t & 7) == 0) {
    const int kpi = t >> 3;
    const float kx = skp[kpi*3+0], ky = skp[kpi*3+1], kz = skp[kpi*3+2];
    const int T = sTot[kpi];

    int c0 = 0, c1 = 0;
    int mi0 = 0x7fffffff, mi1 = 0x7fffffff;
    float p0x = 0.f, p0y = 0.f, p0z = 0.f, p0f = 0.f;
    float p1x = 0.f, p1y = 0.f, p1z = 0.f, p1f = 0.f;
    float M0[14], M1[14];
    #pragma unroll
    for (int i = 0; i < 14; i++) { M0[i] = 0.f; M1[i] = 0.f; }

    for (int j = 0; j < T; ++j) {
      const float4 p = sCand[kpi][j];
      const float dx = p.x - kx, dy = p.y - ky, dz = p.z - kz;
      const float d2 = dx*dx + dy*dy + dz*dz;
      if (d2 < 0.64f) {                 // scale 1 (r=0.8)
        const int pi = sCandI[kpi][j];
        if (c1 < 16) {
          sG1[kpi][c1] = make_float4(dx, dy, dz, p.w);
          ACC14(M1, 1.0f, dx, dy, dz, p.w);
        }
        if (pi < mi1) { mi1 = pi; p1x = dx; p1y = dy; p1z = dz; p1f = p.w; }
        c1++;
        if (d2 < 0.16f) {               // scale 0 (r=0.4)
          if (c0 < 16) {
            sG0[kpi][c0] = make_float4(dx, dy, dz, p.w);
            ACC14(M0, 1.0f, dx, dy, dz, p.w);
          }
          if (pi < mi0) { mi0 = pi; p0x = dx; p0y = dy; p0z = dz; p0f = p.w; }
          c0++;
        }
      }
    }

    // padding: empty -> zeros, partial -> replicate min-idx hit
    {
      const float4 v0 = make_float4(p0x, p0y, p0z, p0f);
      for (int s2 = c0; s2 < 16; ++s2) sG0[kpi][s2] = v0;
      const float w0 = (float)(16 - min(c0, 16));
      ACC14(M0, w0, p0x, p0y, p0z, p0f);
    }
    {
      const float4 v1 = make_float4(p1x, p1y, p1z, p1f);
      for (int s2 = c1; s2 < 16; ++s2) sG1[kpi][s2] = v1;
      const float w1 = (float)(16 - min(c1, 16));
      ACC14(M1, w1, p1x, p1y, p1z, p1f);
    }
    scnt[0][kpi] = c0;
    scnt[1][kpi] = c1;

    // butterfly over lanes {0,8,16,24}: xor distances 8,16
    #pragma unroll
    for (int d = 8; d < 8 * KPB; d <<= 1) {
      #pragma unroll
      for (int i = 0; i < 14; i++) {
        M0[i] += __shfl_xor(M0[i], d);
        M1[i] += __shfl_xor(M1[i], d);
      }
    }
    if (t == 0) {
      float* S0my = S0r + rep * 32;       // stride 32 (line-aligned replicas)
      #pragma unroll
      for (int i = 0; i < 14; i++) {
        ATOMIC_ADD_ACK(&S0my[i],      M0[i]);
        ATOMIC_ADD_ACK(&S0my[14 + i], M1[i]);
      }
    }
  }

  grid_barrier(ctrs, NGRID / NCTR, myc);

  // ---- BN0: distributed replica read (224 threads x 4 loads) ----
  if (t < 224) {
    const int m = t % 28, g = t / 28;     // g in 0..7 -> reps 4g..4g+3
    float a = 0.f;
    #pragma unroll
    for (int r2 = 0; r2 < 4; r2++) a += AL(S0r + (g * 4 + r2) * 32 + m);
    s0p[g][m] = a;
  }
  __syncthreads();
  if (t < 28) {
    float a = 0.f;
    #pragma unroll
    for (int g = 0; g < 8; g++) a += s0p[g][t];
    sS0[t] = a;
  }
  __syncthreads();
  if (t < 32) {
    const int s = t >> 4, c = t & 15;
    const float* W  = s ? sW0b : sW0a;
    const float* G  = s ? gm0s1 : gm0s0;
    const float* Bt = s ? bt0s1 : bt0s0;
    const float* Sx = sS0 + s * 14;
    const float w0 = W[c*4+0], w1 = W[c*4+1];
    const float w2 = W[c*4+2], w3 = W[c*4+3];
    const float inv = 1.0f / MSAMP;
    const float mean = (w0*Sx[0] + w1*Sx[1] + w2*Sx[2] + w3*Sx[3]) * inv;
    float e2 = w0*w0*Sx[4] + 2.f*w0*w1*Sx[5] + 2.f*w0*w2*Sx[6] + 2.f*w0*w3*Sx[7]
             + w1*w1*Sx[8] + 2.f*w1*w2*Sx[9] + 2.f*w1*w3*Sx[10]
             + w2*w2*Sx[11] + 2.f*w2*w3*Sx[12] + w3*w3*Sx[13];
    e2 *= inv;
    const float var = e2 - mean * mean;
    const float A = G[c] / sqrtf(var + 1e-5f);
    sP[s*32 + c]      = A;
    sP[s*32 + 16 + c] = Bt[c] - mean * A;
  }
  __syncthreads();

  // ---- PHASE S: BN1 stats; h2 values kept in registers for phase P ----
  float h2a[16], h2b[32];                 // carried S -> P (same thread map)
  if (t < 16 * KPB) {
    const int lkp = t >> 4, sl = t & 15;
    const int grp = t >> 4;
    const bool leader = (t & 15) == 0;
    float a1[16];
    {  // scale 0
      const float4 x = sG0[lkp][sl];
      #pragma unroll
      for (int c = 0; c < 16; c++) {
        const float h = sW0a[c*4+0]*x.x + sW0a[c*4+1]*x.y + sW0a[c*4+2]*x.z + sW0a[c*4+3]*x.w;
        a1[c] = fmaxf(fmaf(sP[c], h, sP[16+c]), 0.f);
      }
      #pragma unroll
      for (int o = 0; o < 16; o++) {
        float h2 = 0.f;
        #pragma unroll
        for (int c = 0; c < 16; c++) h2 = fmaf(sW1a[o*16+c], a1[c], h2);
        h2a[o] = h2;
        float s = h2, q = h2 * h2;
        #pragma unroll
        for (int d = 1; d < 16; d <<= 1) { s += __shfl_xor(s, d); q += __shfl_xor(q, d); }
        if (leader) { red[grp][o] += s; red[grp][16+o] += q; }
      }
    }
    {  // scale 1
      const float4 x = sG1[lkp][sl];
      #pragma unroll
      for (int c = 0; c < 16; c++) {
        const float h = sW0b[c*4+0]*x.x + sW0b[c*4+1]*x.y + sW0b[c*4+2]*x.z + sW0b[c*4+3]*x.w;
        a1[c] = fmaxf(fmaf(sP[32+c], h, sP[48+c]), 0.f);
      }
      #pragma unroll
      for (int o = 0; o < 32; o++) {
        float h2 = 0.f;
        #pragma unroll
        for (int c = 0; c < 16; c++) h2 = fmaf(sW1b[o*16+c], a1[c], h2);
        h2b[o] = h2;
        float s = h2, q = h2 * h2;
        #pragma unroll
        for (int d = 1; d < 16; d <<= 1) { s += __shfl_xor(s, d); q += __shfl_xor(q, d); }
        if (leader) { red[grp][32+o] += s; red[grp][64+o] += q; }
      }
    }
  }
  __syncthreads();
  if (t < 96) {
    float s = 0.f;
    #pragma unroll
    for (int g = 0; g < KPB; g++) s += red[g][t];
    ATOMIC_ADD_ACK(&S1r[rep * 96 + t], s);
  }

  grid_barrier(ctrs + 2 * NCTR, NGRID / NCTR, myc);

  // ---- BN1: distributed replica read (192 threads x 16 loads, reuse red) --
  if (t < 192) {
    const int v = t % 96, h = t / 96;     // h in {0,1} -> reps 16h..16h+15
    float a = 0.f;
    #pragma unroll
    for (int r2 = 0; r2 < 16; r2++) a += AL(S1r + (h * 16 + r2) * 96 + v);
    red[h][v] = a;
  }
  __syncthreads();
  if (t < 48) {
    float sum, sq, G, Bv; int oA, oB, os, oq;
    if (t < 16) { os = t; oq = 16 + t; G = gm1s0[t]; Bv = bt1s0[t]; oA = 64+t;  oB = 80+t; }
    else { const int c = t - 16; os = 32 + c; oq = 64 + c; G = gm1s1[c]; Bv = bt1s1[c]; oA = 96+c; oB = 128+c; }
    sum = red[0][os] + red[1][os];
    sq  = red[0][oq] + red[1][oq];
    const float mean = sum / MSAMP;
    const float var  = sq / MSAMP - mean * mean;
    const float A = G / sqrtf(var + 1e-5f);
    sP[oA] = A;
    sP[oB] = Bv - mean * A;
  }
  __syncthreads();

  // ---- PHASE P pool from carried h2 (no MLP recompute) ----
  if (t < 16 * KPB) {
    const int lkp = t >> 4, slot = t & 15;
    float a2s0[16], a2s1[32];
    #pragma unroll
    for (int o = 0; o < 16; o++) a2s0[o] = fmaxf(fmaf(sP[64+o], h2a[o], sP[80+o]), 0.f);
    #pragma unroll
    for (int o = 0; o < 32; o++) a2s1[o] = fmaxf(fmaf(sP[96+o], h2b[o], sP[128+o]), 0.f);
    #pragma unroll
    for (int d = 1; d < 16; d <<= 1) {
      #pragma unroll
      for (int o = 0; o < 16; o++) a2s0[o] = fmaxf(a2s0[o], __shfl_xor(a2s0[o], d));
      #pragma unroll
      for (int o = 0; o < 32; o++) a2s1[o] = fmaxf(a2s1[o], __shfl_xor(a2s1[o], d));
    }
    if (slot == 0) {
      const int c0 = scnt[0][lkp], c1 = scnt[1][lkp];
      float* outp = sF + lkp * 304 + 256;
      #pragma unroll
      for (int o = 0; o < 16; o++) outp[o] = c0 ? a2s0[o] : 0.f;
      #pragma unroll
      for (int o = 0; o < 32; o++) outp[16 + o] = c1 ? a2s1[o] : 0.f;
    }
  }
  __syncthreads();

  // ---- GEMM phase: col c = t&127, rows rbase..rbase+1 ----
  const int c = t & 127;
  const int half = t >> 7;
  const int rbase = half * 2;
  float acc[2];
  {
    #pragma unroll
    for (int r = 0; r < 2; r++) acc[r] = 0.f;
    const float* wrow = Wf + (size_t)c * 304;
    for (int j4 = 0; j4 < 76; j4++) {
      const float4 w = *(const float4*)(wrow + j4 * 4);
      #pragma unroll
      for (int r = 0; r < 2; r++) {
        const float4 f = *(const float4*)(sF + (rbase + r) * 304 + j4 * 4);
        acc[r] = fmaf(w.x, f.x, acc[r]);
        acc[r] = fmaf(w.y, f.y, acc[r]);
        acc[r] = fmaf(w.z, f.z, acc[r]);
        acc[r] = fmaf(w.w, f.w, acc[r]);
      }
    }
    float s = 0.f, q = 0.f;
    #pragma unroll
    for (int r = 0; r < 2; r++) {
      s += acc[r];
      q = fmaf(acc[r], acc[r], q);
    }
    t2s[half][c] = s;
    t2q[half][c] = q;
  }
  __syncthreads();
  if (t < 128) {
    ATOMIC_ADD_ACK(&S2sr[rep * 128 + t], t2s[0][t] + t2s[1][t]);
    ATOMIC_ADD_ACK(&S2qr[rep * 128 + t], t2q[0][t] + t2q[1][t]);
  }

  grid_barrier(ctrs + 4 * NCTR, NGRID / NCTR, myc);

  // ---- final BN: distributed replica read (256 threads x 32 loads) ----
  {
    const int v = t & 127;
    const float* Sx = (t < 128) ? S2sr : S2qr;
    float a = 0.f;
    #pragma unroll
    for (int r = 0; r < NREP; r++) a += AL(Sx + r * 128 + v);
    if (t < 128) t2s[0][v] = a; else t2q[0][v] = a;
  }
  __syncthreads();
  if (t < 128) {
    const float mean = t2s[0][t] / MROW;
    const float var  = t2q[0][t] / MROW - mean * mean;
    const float A = gf[t] / sqrtf(var + 1e-5f);
    sA[t] = A;
    sB[t] = bfp[t] - mean * A;
  }
  __syncthreads();
  {
    const float A = sA[c], B = sB[c];
    #pragma unroll
    for (int r = 0; r < 2; r++) {
      out[(size_t)(bk0 + rbase + r) * 128 + c] = fmaxf(fmaf(acc[r], A, B), 0.f);
    }
  }
}

// ---------------------------------------------------------------------------
extern "C" void kernel_launch(void* const* d_in, const int* in_sizes, int n_in,
                              void* d_out, int out_size, void* d_ws, size_t ws_size,
                              hipStream_t stream)
{
  const float* kp    = (const float*)d_in[0];
  const float* pts   = (const float*)d_in[1];
  const float* pfeat = (const float*)d_in[2];
  const float* bev   = (const float*)d_in[3];
  const int*   strd  = (const int*)d_in[4];
  const float* W0s0  = (const float*)d_in[5];
  const float* g0s0  = (const float*)d_in[6];
  const float* b0s0  = (const float*)d_in[7];
  const float* W1s0  = (const float*)d_in[8];
  const float* g1s0  = (const float*)d_in[9];
  const float* b1s0  = (const float*)d_in[10];
  const float* W0s1  = (const float*)d_in[11];
  const float* g0s1  = (const float*)d_in[12];
  const float* b0s1  = (const float*)d_in[13];
  const float* W1s1  = (const float*)d_in[14];
  const float* g1s1  = (const float*)d_in[15];
  const float* b1s1  = (const float*)d_in[16];
  const float* Wf    = (const float*)d_in[17];
  const float* gf    = (const float*)d_in[18];
  const float* bfv   = (const float*)d_in[19];

  float* w = (float*)d_ws;
  // zeroed region (one memset):
  //   cellcnt[2*NCELLS]                      35552 ints
  //   ctrs[3 * 2*NCTR]  (ctr+rel per bar)    384 ints
  //   S0r[NREP*32] S1r[NREP*96] S2sr/S2qr[NREP*128 each]
  int*   cellcnt = (int*)(w + 1048576);
  int*   ctrs    = cellcnt + 2 * NCELLS;
  float* S0r     = (float*)(ctrs + 6 * NCTR);
  float* S1r     = S0r + NREP * 32;
  float* S2sr    = S1r + NREP * 96;
  float* S2qr    = S2sr + NREP * 128;
  const size_t zero_elems = 2 * NCELLS + 6 * NCTR
                          + NREP * (32 + 96 + 128 + 128);

  float*  bevT    = w + 1245184;             // 2*17600*256 floats = 36 MB
  float4* bucketP = (float4*)(w + 10256384); // 2*NCELLS*CAP float4 = 13.7 MB
  int*    bucketI = (int*)(w + 10256384 + (size_t)2 * NCELLS * CAP * 4);

  hipMemsetAsync(cellcnt, 0, zero_elems * sizeof(int), stream);
  hipLaunchKernelGGL(bintrans_kernel, dim3(2328), dim3(256), 0, stream,
                     pts, pfeat, bev, cellcnt, bucketP, bucketI, bevT);
  hipLaunchKernelGGL(fused_kernel, dim3(NGRID), dim3(256), 0, stream,
                     kp, strd, bevT, cellcnt, bucketP, bucketI,
                     W0s0, g0s0, b0s0, W0s1, g0s1, b0s1,
                     W1s0, g1s0, b1s0, W1s1, g1s1, b1s1,
                     Wf, gf, bfv, S0r, S1r, S2sr, S2qr, ctrs, (float*)d_out);
}

// Round 13
// 180.005 us; speedup vs baseline: 1.0990x; 1.0990x over previous
//
#include <hip/hip_runtime.h>
#include <hip/hip_bf16.h>

#define NB    2
#define NK    2048
#define NPTS  16384
#define NBK   4096            // NB*NK
#define MSAMP 65536.0f        // NBK*16 samples per scale for BN0/BN1
#define MROW  4096.0f         // rows for final BN

// spatial binning grid: cell = 0.8 (== r1), origin (-70.4, -40.0)
#define NCELLX 176
#define NCELLY 101
#define NCELLS 17776          // 176*101
#define CAP    24             // bucket capacity (mean 0.94 pts/cell; tail ~0)
#define CANDMAX 64            // staged candidates per keypoint (avg ~8.3)

#define NREP   32             // stats replicas (RMW chain depth 16)
#define NCTR   64             // split barrier counters (chain depth 8)

// device-scope (agent) relaxed atomic load — reads the coherence point.
#define AL(p) __hip_atomic_load((p), __ATOMIC_RELAXED, __HIP_MEMORY_SCOPE_AGENT)

// RETURNING atomic with sunk result: ack arrives only after the op is
// PERFORMED at the coherence point, so a following s_waitcnt vmcnt(0) gives
// "my writes are globally visible" (r4 post-mortem; r5..r12 proved it).
#define ATOMIC_ADD_ACK(p, v) do { \
  float _r = atomicAdd((p), (v)); \
  asm volatile("" :: "v"(_r)); } while (0)

// accumulate 14 BN0 moments (order matches bn0-param consumption)
#define ACC14(M, w, X, Y, Z, F) do { \
  M[0] += (w)*(X); M[1] += (w)*(Y); M[2] += (w)*(Z); M[3] += (w)*(F); \
  M[4] += (w)*(X)*(X); M[5] += (w)*(X)*(Y); M[6] += (w)*(X)*(Z); M[7] += (w)*(X)*(F); \
  M[8] += (w)*(Y)*(Y); M[9] += (w)*(Y)*(Z); M[10] += (w)*(Y)*(F); \
  M[11] += (w)*(Z)*(Z); M[12] += (w)*(Z)*(F); M[13] += (w)*(F)*(F); } while (0)

__device__ __forceinline__ int cell_of(float x, float y) {
  int cx = (int)floorf((x + 70.4f) * 1.25f);
  int cy = (int)floorf((y + 40.0f) * 1.25f);
  cx = min(max(cx, 0), NCELLX - 1);
  cy = min(max(cy, 0), NCELLY - 1);
  return cy * NCELLX + cx;
}

// Two-stage release-flag grid barrier (r7..r11-verified). Layout per
// instance: base[0..63] = counters, base[64..127] = release flags.
__device__ __forceinline__ void grid_barrier(int* base, int per, int myc) {
  asm volatile("s_waitcnt vmcnt(0)" ::: "memory");
  __syncthreads();
  const int t = threadIdx.x;
  int* ctr = base;
  int* rel = base + NCTR;
  if (t == 0) {
    int old = __hip_atomic_fetch_add(&ctr[myc], 1, __ATOMIC_RELAXED,
                                     __HIP_MEMORY_SCOPE_AGENT);
    asm volatile("" :: "v"(old));
  }
  if (blockIdx.x == 0) {
    if (t < NCTR) {
      while (AL(&ctr[t]) < per) __builtin_amdgcn_s_sleep(8);
    }
    __syncthreads();           // all counters observed by the whole block
    if (t < NCTR)
      __hip_atomic_store(&rel[t], 1, __ATOMIC_RELAXED,
                         __HIP_MEMORY_SCOPE_AGENT);
  } else {
    if (t == 0) {
      while (AL(&rel[myc]) == 0) __builtin_amdgcn_s_sleep(8);
    }
  }
  __syncthreads();
}

// ---------------------------------------------------------------------------
// K1: direct bucket-build (blocks 0..127) + BEV CHW->HWC transpose
// (blocks 128..2327), FLOAT4 both sides (r11-verified, ~13us BW-bound).
// cellcnt zeroed by the preceding memset.
// ---------------------------------------------------------------------------
__global__ __launch_bounds__(256) void bintrans_kernel(
    const float* __restrict__ pts, const float* __restrict__ pfeat,
    const float* __restrict__ bev,
    int* __restrict__ cellcnt, float4* __restrict__ bucketP,
    int* __restrict__ bucketI, float* __restrict__ bevT)
{
  __shared__ __align__(16) float ttile[64][65];
  const int t = threadIdx.x;

  if (blockIdx.x < 128) {
    const int i  = blockIdx.x * 256 + t;      // 0..32767
    const int b  = i >> 14;
    const int il = i & (NPTS - 1);
    const float* px = pts + (size_t)b * NPTS * 3;
    const float x = px[il*3+0], y = px[il*3+1], z = px[il*3+2];
    const float f = pfeat[(size_t)b * NPTS + il];
    const int c = b * NCELLS + cell_of(x, y);
    const int pos = atomicAdd(&cellcnt[c], 1);
    if (pos < CAP) {
      bucketP[(size_t)c * CAP + pos] = make_float4(x, y, z, f);
      bucketI[(size_t)c * CAP + pos] = il;
    }
    return;
  }

  // ---- TRANSPOSE role, float4 loads (along spatial) + float4 stores
  // (across channels). LDS: 2-way bank aliasing both phases (free, m136).
  const int tb  = blockIdx.x - 128;     // 0..2199
  const int b   = tb / 1100;
  const int rem = tb % 1100;
  const int cg  = (rem / 275) * 64;     // channel group base
  const int sp0 = (rem % 275) * 64;     // spatial base (17600 = 275*64)
  const int lo = t & 15, hi = t >> 4;
  #pragma unroll
  for (int pass = 0; pass < 4; pass++) {
    const int ch = hi + pass * 16;      // 0..63
    const float4 v = *(const float4*)&bev[
        ((size_t)(b * 256 + cg + ch)) * 17600 + sp0 + lo * 4];
    ttile[ch][lo*4+0] = v.x;
    ttile[ch][lo*4+1] = v.y;
    ttile[ch][lo*4+2] = v.z;
    ttile[ch][lo*4+3] = v.w;
  }
  __syncthreads();
  #pragma unroll
  for (int pass = 0; pass < 4; pass++) {
    const int s = hi + pass * 16;       // 0..63
    float4 v;
    v.x = ttile[lo*4+0][s];
    v.y = ttile[lo*4+1][s];
    v.z = ttile[lo*4+2][s];
    v.w = ttile[lo*4+3][s];
    *(float4*)&bevT[((size_t)b * 17600 + sp0 + s) * 256 + cg + lo * 4] = v;
  }
}

// ---------------------------------------------------------------------------
// K2: mega-fused (r8/r11-verified, ~66us). grid 512 x 256, 8 keypoints/block.
// Grid-size bracketed: 512x8kp=66us optimum; 1024x4kp=111us (r12: per-block
// fixed costs — weights, Wf, replica reads, barrier arrivals — double with
// block count and dominate; occupancy was NOT binding); more kernel splits
// re-add ~14us/dispatch (r2/r10).
//   [gather BEV from bevT] [G-stage: 64 lanes prefetch candidates -> LDS]
//   [G-process: 8 lanes slot-assign, S0 adds]
//   bar0 [BN0: distributed replica read] [S: BN1 stats, h2 kept in regs]
//   bar1 [BN1: distributed replica read] [P: pool from carried h2; GEMM; S2]
//   bar2 [final BN: distributed replica read; relu; out from acc regs]
// Sync protocol r5..r11-verified; stats replicated x32.
// Grouping correctness vs reference: for cnt<=16 the slot SET is exact
// (order-free; BN stats sum over slots, pool is max); padding replicates the
// min-original-index hit == ref's idx[:, :1]; empty -> zeros.
// ---------------------------------------------------------------------------
__global__ __launch_bounds__(256, 2) void fused_kernel(
    const float* __restrict__ kp, const int* __restrict__ stridep,
    const float* __restrict__ bevT,
    const int* __restrict__ cellcnt, const float4* __restrict__ bucketP,
    const int* __restrict__ bucketI,
    const float* __restrict__ W0s0, const float* __restrict__ gm0s0, const float* __restrict__ bt0s0,
    const float* __restrict__ W0s1, const float* __restrict__ gm0s1, const float* __restrict__ bt0s1,
    const float* __restrict__ W1s0, const float* __restrict__ gm1s0, const float* __restrict__ bt1s0,
    const float* __restrict__ W1s1, const float* __restrict__ gm1s1, const float* __restrict__ bt1s1,
    const float* __restrict__ Wf, const float* __restrict__ gf, const float* __restrict__ bfp,
    float* __restrict__ S0r, float* __restrict__ S1r,
    float* __restrict__ S2sr, float* __restrict__ S2qr,
    int* __restrict__ ctrs, float* __restrict__ out)
{
  __shared__ float sW0a[64], sW0b[64], sW1a[256], sW1b[512], sP[160];
  __shared__ float skp[24];
  __shared__ float red[8][96];
  __shared__ float t2s[2][128], t2q[2][128];
  __shared__ float sA[128], sB[128];
  __shared__ float s0p[8][28], sS0[28];
  __shared__ __align__(16) float sF[8 * 304];
  __shared__ float4 sG0[8][16], sG1[8][16];
  __shared__ __align__(16) float4 sCand[8][CANDMAX];
  __shared__ int sCandI[8][CANDMAX];
  __shared__ int sTot[8];
  __shared__ int scnt[2][8];
  const int t = threadIdx.x;
  const int bk0 = blockIdx.x * 8;
  const int rep = blockIdx.x & (NREP - 1);
  const int myc = blockIdx.x & (NCTR - 1);

  if (t < 24) skp[t] = kp[(size_t)bk0 * 3 + t];
  if (t < 64) { sW0a[t] = W0s0[t]; sW0b[t] = W0s1[t]; }
  sW1a[t]       = W1s0[t];
  sW1b[t]       = W1s1[t];
  sW1b[t + 256] = W1s1[t + 256];
  for (int i = t; i < 8 * 96; i += 256) ((float*)red)[i] = 0.f;
  __syncthreads();

  // ---- BEV gather from bevT (HWC): channel t, 8 rows, 32 coalesced loads --
  {
    const float st = (float)(*stridep);
    const int b = bk0 >> 11;             // all 8 rows in same batch (8 | 2048)
    const size_t pb = (size_t)b * 17600 * 256;
    #pragma unroll
    for (int r = 0; r < 8; r++) {
      const float x = (skp[r*3+0] - (-70.4f)) / 0.1f / st;
      const float y = (skp[r*3+1] - (-40.0f)) / 0.1f / st;
      const int xf = (int)floorf(x), yf = (int)floorf(y);
      const int x0 = min(max(xf, 0), 175), x1 = min(max(xf + 1, 0), 175);
      const int y0 = min(max(yf, 0), 99),  y1 = min(max(yf + 1, 0), 99);
      const float x0f = (float)x0, x1f = (float)x1, y0f = (float)y0, y1f = (float)y1;
      const float wa = (x1f - x) * (y1f - y);
      const float wb = (x1f - x) * (y - y0f);
      const float wc = (x - x0f) * (y1f - y);
      const float wd = (x - x0f) * (y - y0f);
      const float Ia = bevT[pb + (size_t)(y0 * 176 + x0) * 256 + t];
      const float Ib = bevT[pb + (size_t)(y1 * 176 + x0) * 256 + t];
      const float Ic = bevT[pb + (size_t)(y0 * 176 + x1) * 256 + t];
      const float Id = bevT[pb + (size_t)(y1 * 176 + x1) * 256 + t];
      sF[r * 304 + t] = Ia * wa + Ib * wb + Ic * wc + Id * wd;
    }
  }

  // ---- PHASE G-stage: 8 lanes per keypoint prefetch candidates to LDS ----
  if (t < 64) {
    const int kpi = t >> 3, sub = t & 7;
    const int b   = (bk0 + kpi) >> 11;
    const float kx = skp[kpi*3+0], ky = skp[kpi*3+1];
    int cx = (int)floorf((kx + 70.4f) * 1.25f);
    int cy = (int)floorf((ky + 40.0f) * 1.25f);
    cx = min(max(cx, 1), NCELLX - 2);
    cy = min(max(cy, 1), NCELLY - 2);
    const int cb0 = b * NCELLS + (cy - 1) * NCELLX + cx - 1;
    // 3x3 window, row-major c9=0..8; lane sub owns c9=sub, lane 0 also c9=8
    const int cellS = cb0 + (sub / 3) * NCELLX + (sub % 3);
    const int cell8 = cb0 + 2 * NCELLX + 2;
    const int nS = min(cellcnt[cellS], CAP);
    const int n8 = (sub == 0) ? min(cellcnt[cell8], CAP) : 0;
    // exclusive prefix of nS within the 8-lane group
    int pre = nS;
    #pragma unroll
    for (int d = 1; d < 8; d <<= 1) {
      const int v = __shfl_up(pre, d, 8);
      if (sub >= d) pre += v;
    }
    const int offS  = pre - nS;
    const int tot07 = __shfl(pre, 7, 8);
    const float4* bp = bucketP + (size_t)cellS * CAP;
    const int*    bi = bucketI + (size_t)cellS * CAP;
    for (int j = 0; j < nS; ++j) {
      const int o = offS + j;
      if (o < CANDMAX) { sCand[kpi][o] = bp[j]; sCandI[kpi][o] = bi[j]; }
    }
    if (sub == 0) {
      const float4* bp8 = bucketP + (size_t)cell8 * CAP;
      const int*    bi8 = bucketI + (size_t)cell8 * CAP;
      for (int j = 0; j < n8; ++j) {
        const int o = tot07 + j;
        if (o < CANDMAX) { sCand[kpi][o] = bp8[j]; sCandI[kpi][o] = bi8[j]; }
      }
      sTot[kpi] = min(tot07 + n8, CANDMAX);
    }
  }
  __syncthreads();

  // ---- PHASE G-process: 1 lane/kp, order-dependent slot pass from LDS ----
  if (t < 64 && (t & 7) == 0) {
    const int kpi = t >> 3;
    const float kx = skp[kpi*3+0], ky = skp[kpi*3+1], kz = skp[kpi*3+2];
    const int T = sTot[kpi];

    int c0 = 0, c1 = 0;
    int mi0 = 0x7fffffff, mi1 = 0x7fffffff;
    float p0x = 0.f, p0y = 0.f, p0z = 0.f, p0f = 0.f;
    float p1x = 0.f, p1y = 0.f, p1z = 0.f, p1f = 0.f;
    float M0[14], M1[14];
    #pragma unroll
    for (int i = 0; i < 14; i++) { M0[i] = 0.f; M1[i] = 0.f; }

    for (int j = 0; j < T; ++j) {
      const float4 p = sCand[kpi][j];
      const float dx = p.x - kx, dy = p.y - ky, dz = p.z - kz;
      const float d2 = dx*dx + dy*dy + dz*dz;
      if (d2 < 0.64f) {                 // scale 1 (r=0.8)
        const int pi = sCandI[kpi][j];
        if (c1 < 16) {
          sG1[kpi][c1] = make_float4(dx, dy, dz, p.w);
          ACC14(M1, 1.0f, dx, dy, dz, p.w);
        }
        if (pi < mi1) { mi1 = pi; p1x = dx; p1y = dy; p1z = dz; p1f = p.w; }
        c1++;
        if (d2 < 0.16f) {               // scale 0 (r=0.4)
          if (c0 < 16) {
            sG0[kpi][c0] = make_float4(dx, dy, dz, p.w);
            ACC14(M0, 1.0f, dx, dy, dz, p.w);
          }
          if (pi < mi0) { mi0 = pi; p0x = dx; p0y = dy; p0z = dz; p0f = p.w; }
          c0++;
        }
      }
    }

    // padding: empty -> zeros, partial -> replicate min-idx hit
    {
      const float4 v0 = make_float4(p0x, p0y, p0z, p0f);
      for (int s2 = c0; s2 < 16; ++s2) sG0[kpi][s2] = v0;
      const float w0 = (float)(16 - min(c0, 16));
      ACC14(M0, w0, p0x, p0y, p0z, p0f);
    }
    {
      const float4 v1 = make_float4(p1x, p1y, p1z, p1f);
      for (int s2 = c1; s2 < 16; ++s2) sG1[kpi][s2] = v1;
      const float w1 = (float)(16 - min(c1, 16));
      ACC14(M1, w1, p1x, p1y, p1z, p1f);
    }
    scnt[0][kpi] = c0;
    scnt[1][kpi] = c1;

    // butterfly over lanes {0,8,...,56}: xor distances 8,16,32
    #pragma unroll
    for (int d = 8; d < 64; d <<= 1) {
      #pragma unroll
      for (int i = 0; i < 14; i++) {
        M0[i] += __shfl_xor(M0[i], d);
        M1[i] += __shfl_xor(M1[i], d);
      }
    }
    if (t == 0) {
      float* S0my = S0r + rep * 32;       // stride 32 (line-aligned replicas)
      #pragma unroll
      for (int i = 0; i < 14; i++) {
        ATOMIC_ADD_ACK(&S0my[i],      M0[i]);
        ATOMIC_ADD_ACK(&S0my[14 + i], M1[i]);
      }
    }
  }

  grid_barrier(ctrs, 512 / NCTR, myc);

  // ---- BN0: distributed replica read (224 threads x 4 loads) ----
  if (t < 224) {
    const int m = t % 28, g = t / 28;     // g in 0..7 -> reps 4g..4g+3
    float a = 0.f;
    #pragma unroll
    for (int r2 = 0; r2 < 4; r2++) a += AL(S0r + (g * 4 + r2) * 32 + m);
    s0p[g][m] = a;
  }
  __syncthreads();
  if (t < 28) {
    float a = 0.f;
    #pragma unroll
    for (int g = 0; g < 8; g++) a += s0p[g][t];
    sS0[t] = a;
  }
  __syncthreads();
  if (t < 32) {
    const int s = t >> 4, c = t & 15;
    const float* W  = s ? sW0b : sW0a;
    const float* G  = s ? gm0s1 : gm0s0;
    const float* Bt = s ? bt0s1 : bt0s0;
    const float* Sx = sS0 + s * 14;
    const float w0 = W[c*4+0], w1 = W[c*4+1];
    const float w2 = W[c*4+2], w3 = W[c*4+3];
    const float inv = 1.0f / MSAMP;
    const float mean = (w0*Sx[0] + w1*Sx[1] + w2*Sx[2] + w3*Sx[3]) * inv;
    float e2 = w0*w0*Sx[4] + 2.f*w0*w1*Sx[5] + 2.f*w0*w2*Sx[6] + 2.f*w0*w3*Sx[7]
             + w1*w1*Sx[8] + 2.f*w1*w2*Sx[9] + 2.f*w1*w3*Sx[10]
             + w2*w2*Sx[11] + 2.f*w2*w3*Sx[12] + w3*w3*Sx[13];
    e2 *= inv;
    const float var = e2 - mean * mean;
    const float A = G[c] / sqrtf(var + 1e-5f);
    sP[s*32 + c]      = A;
    sP[s*32 + 16 + c] = Bt[c] - mean * A;
  }
  __syncthreads();

  // ---- PHASE S: BN1 stats; h2 values kept in registers for phase P ----
  float h2a[16], h2b[32];                 // carried S -> P (same thread map)
  if (t < 128) {
    const int lkp = t >> 4, sl = t & 15;
    const int grp = t >> 4;
    const bool leader = (t & 15) == 0;
    float a1[16];
    {  // scale 0
      const float4 x = sG0[lkp][sl];
      #pragma unroll
      for (int c = 0; c < 16; c++) {
        const float h = sW0a[c*4+0]*x.x + sW0a[c*4+1]*x.y + sW0a[c*4+2]*x.z + sW0a[c*4+3]*x.w;
        a1[c] = fmaxf(fmaf(sP[c], h, sP[16+c]), 0.f);
      }
      #pragma unroll
      for (int o = 0; o < 16; o++) {
        float h2 = 0.f;
        #pragma unroll
        for (int c = 0; c < 16; c++) h2 = fmaf(sW1a[o*16+c], a1[c], h2);
        h2a[o] = h2;
        float s = h2, q = h2 * h2;
        #pragma unroll
        for (int d = 1; d < 16; d <<= 1) { s += __shfl_xor(s, d); q += __shfl_xor(q, d); }
        if (leader) { red[grp][o] += s; red[grp][16+o] += q; }
      }
    }
    {  // scale 1
      const float4 x = sG1[lkp][sl];
      #pragma unroll
      for (int c = 0; c < 16; c++) {
        const float h = sW0b[c*4+0]*x.x + sW0b[c*4+1]*x.y + sW0b[c*4+2]*x.z + sW0b[c*4+3]*x.w;
        a1[c] = fmaxf(fmaf(sP[32+c], h, sP[48+c]), 0.f);
      }
      #pragma unroll
      for (int o = 0; o < 32; o++) {
        float h2 = 0.f;
        #pragma unroll
        for (int c = 0; c < 16; c++) h2 = fmaf(sW1b[o*16+c], a1[c], h2);
        h2b[o] = h2;
        float s = h2, q = h2 * h2;
        #pragma unroll
        for (int d = 1; d < 16; d <<= 1) { s += __shfl_xor(s, d); q += __shfl_xor(q, d); }
        if (leader) { red[grp][32+o] += s; red[grp][64+o] += q; }
      }
    }
  }
  __syncthreads();
  if (t < 96) {
    float s = 0.f;
    #pragma unroll
    for (int g = 0; g < 8; g++) s += red[g][t];
    ATOMIC_ADD_ACK(&S1r[rep * 96 + t], s);
  }

  grid_barrier(ctrs + 2 * NCTR, 512 / NCTR, myc);

  // ---- BN1: distributed replica read (192 threads x 16 loads, reuse red) --
  if (t < 192) {
    const int v = t % 96, h = t / 96;     // h in {0,1} -> reps 16h..16h+15
    float a = 0.f;
    #pragma unroll
    for (int r2 = 0; r2 < 16; r2++) a += AL(S1r + (h * 16 + r2) * 96 + v);
    red[h][v] = a;
  }
  __syncthreads();
  if (t < 48) {
    float sum, sq, G, Bv; int oA, oB, os, oq;
    if (t < 16) { os = t; oq = 16 + t; G = gm1s0[t]; Bv = bt1s0[t]; oA = 64+t;  oB = 80+t; }
    else { const int c = t - 16; os = 32 + c; oq = 64 + c; G = gm1s1[c]; Bv = bt1s1[c]; oA = 96+c; oB = 128+c; }
    sum = red[0][os] + red[1][os];
    sq  = red[0][oq] + red[1][oq];
    const float mean = sum / MSAMP;
    const float var  = sq / MSAMP - mean * mean;
    const float A = G / sqrtf(var + 1e-5f);
    sP[oA] = A;
    sP[oB] = Bv - mean * A;
  }
  __syncthreads();

  // ---- PHASE P pool from carried h2 (no MLP recompute) ----
  if (t < 128) {
    const int lkp = t >> 4, slot = t & 15;
    float a2s0[16], a2s1[32];
    #pragma unroll
    for (int o = 0; o < 16; o++) a2s0[o] = fmaxf(fmaf(sP[64+o], h2a[o], sP[80+o]), 0.f);
    #pragma unroll
    for (int o = 0; o < 32; o++) a2s1[o] = fmaxf(fmaf(sP[96+o], h2b[o], sP[128+o]), 0.f);
    #pragma unroll
    for (int d = 1; d < 16; d <<= 1) {
      #pragma unroll
      for (int o = 0; o < 16; o++) a2s0[o] = fmaxf(a2s0[o], __shfl_xor(a2s0[o], d));
      #pragma unroll
      for (int o = 0; o < 32; o++) a2s1[o] = fmaxf(a2s1[o], __shfl_xor(a2s1[o], d));
    }
    if (slot == 0) {
      const int c0 = scnt[0][lkp], c1 = scnt[1][lkp];
      float* outp = sF + lkp * 304 + 256;
      #pragma unroll
      for (int o = 0; o < 16; o++) outp[o] = c0 ? a2s0[o] : 0.f;
      #pragma unroll
      for (int o = 0; o < 32; o++) outp[16 + o] = c1 ? a2s1[o] : 0.f;
    }
  }
  __syncthreads();

  // ---- GEMM phase: col c = t&127, rows rbase..rbase+4 ----
  const int c = t & 127;
  const int half = t >> 7;
  const int rbase = half * 4;
  float acc[4];
  {
    #pragma unroll
    for (int r = 0; r < 4; r++) acc[r] = 0.f;
    const float* wrow = Wf + (size_t)c * 304;
    for (int j4 = 0; j4 < 76; j4++) {
      const float4 w = *(const float4*)(wrow + j4 * 4);
      #pragma unroll
      for (int r = 0; r < 4; r++) {
        const float4 f = *(const float4*)(sF + (rbase + r) * 304 + j4 * 4);
        acc[r] = fmaf(w.x, f.x, acc[r]);
        acc[r] = fmaf(w.y, f.y, acc[r]);
        acc[r] = fmaf(w.z, f.z, acc[r]);
        acc[r] = fmaf(w.w, f.w, acc[r]);
      }
    }
    float s = 0.f, q = 0.f;
    #pragma unroll
    for (int r = 0; r < 4; r++) {
      s += acc[r];
      q = fmaf(acc[r], acc[r], q);
    }
    t2s[half][c] = s;
    t2q[half][c] = q;
  }
  __syncthreads();
  if (t < 128) {
    ATOMIC_ADD_ACK(&S2sr[rep * 128 + t], t2s[0][t] + t2s[1][t]);
    ATOMIC_ADD_ACK(&S2qr[rep * 128 + t], t2q[0][t] + t2q[1][t]);
  }

  grid_barrier(ctrs + 4 * NCTR, 512 / NCTR, myc);

  // ---- final BN: distributed replica read (256 threads x 32 loads) ----
  {
    const int v = t & 127;
    const float* Sx = (t < 128) ? S2sr : S2qr;
    float a = 0.f;
    #pragma unroll
    for (int r = 0; r < NREP; r++) a += AL(Sx + r * 128 + v);
    if (t < 128) t2s[0][v] = a; else t2q[0][v] = a;
  }
  __syncthreads();
  if (t < 128) {
    const float mean = t2s[0][t] / MROW;
    const float var  = t2q[0][t] / MROW - mean * mean;
    const float A = gf[t] / sqrtf(var + 1e-5f);
    sA[t] = A;
    sB[t] = bfp[t] - mean * A;
  }
  __syncthreads();
  {
    const float A = sA[c], B = sB[c];
    #pragma unroll
    for (int r = 0; r < 4; r++) {
      out[(size_t)(bk0 + rbase + r) * 128 + c] = fmaxf(fmaf(acc[r], A, B), 0.f);
    }
  }
}

// ---------------------------------------------------------------------------
extern "C" void kernel_launch(void* const* d_in, const int* in_sizes, int n_in,
                              void* d_out, int out_size, void* d_ws, size_t ws_size,
                              hipStream_t stream)
{
  const float* kp    = (const float*)d_in[0];
  const float* pts   = (const float*)d_in[1];
  const float* pfeat = (const float*)d_in[2];
  const float* bev   = (const float*)d_in[3];
  const int*   strd  = (const int*)d_in[4];
  const float* W0s0  = (const float*)d_in[5];
  const float* g0s0  = (const float*)d_in[6];
  const float* b0s0  = (const float*)d_in[7];
  const float* W1s0  = (const float*)d_in[8];
  const float* g1s0  = (const float*)d_in[9];
  const float* b1s0  = (const float*)d_in[10];
  const float* W0s1  = (const float*)d_in[11];
  const float* g0s1  = (const float*)d_in[12];
  const float* b0s1  = (const float*)d_in[13];
  const float* W1s1  = (const float*)d_in[14];
  const float* g1s1  = (const float*)d_in[15];
  const float* b1s1  = (const float*)d_in[16];
  const float* Wf    = (const float*)d_in[17];
  const float* gf    = (const float*)d_in[18];
  const float* bfv   = (const float*)d_in[19];

  float* w = (float*)d_ws;
  // zeroed region (one memset):
  //   cellcnt[2*NCELLS]                      35552 ints
  //   ctrs[3 * 2*NCTR]  (ctr+rel per bar)    384 ints
  //   S0r[NREP*32] S1r[NREP*96] S2sr/S2qr[NREP*128 each]
  int*   cellcnt = (int*)(w + 1048576);
  int*   ctrs    = cellcnt + 2 * NCELLS;
  float* S0r     = (float*)(ctrs + 6 * NCTR);
  float* S1r     = S0r + NREP * 32;
  float* S2sr    = S1r + NREP * 96;
  float* S2qr    = S2sr + NREP * 128;
  const size_t zero_elems = 2 * NCELLS + 6 * NCTR
                          + NREP * (32 + 96 + 128 + 128);

  float*  bevT    = w + 1245184;             // 2*17600*256 floats = 36 MB
  float4* bucketP = (float4*)(w + 10256384); // 2*NCELLS*CAP float4 = 13.7 MB
  int*    bucketI = (int*)(w + 10256384 + (size_t)2 * NCELLS * CAP * 4);

  hipMemsetAsync(cellcnt, 0, zero_elems * sizeof(int), stream);
  hipLaunchKernelGGL(bintrans_kernel, dim3(2328), dim3(256), 0, stream,
                     pts, pfeat, bev, cellcnt, bucketP, bucketI, bevT);
  hipLaunchKernelGGL(fused_kernel, dim3(512), dim3(256), 0, stream,
                     kp, strd, bevT, cellcnt, bucketP, bucketI,
                     W0s0, g0s0, b0s0, W0s1, g0s1, b0s1,
                     W1s0, g1s0, b1s0, W1s1, g1s1, b1s1,
                     Wf, gf, bfv, S0r, S1r, S2sr, S2qr, ctrs, (float*)d_out);
}